// Round 3
// baseline (105552.991 us; speedup 1.0000x reference)
//
#include <hip/hip_runtime.h>
#include <stdint.h>

typedef short short8 __attribute__((ext_vector_type(8)));
typedef unsigned short u16;

#define T_LEN 512
#define BATCH 64
#define EMB_D 512
#define HID 1024
#define VOC 256

// -------- workspace layout (bytes) --------
#define OFF_H0F   0u                         // float h0[2][64][1024]
#define OFF_H1F   524288u                    // float h1[2][64][1024]
#define OFF_H0B   1048576u                   // bf16  h0[2][64][1024]
#define OFF_H1B   1310720u                   // bf16  h1[2][64][1024]
#define ZERO_BYTES 1573120u
#define OFF_EMB   1573120u                   // bf16 emb_all[512][64][512]
#define OFF_WIH0  (OFF_EMB + 33554432u)
#define OFF_WHH0  (OFF_WIH0 + 3145728u)
#define OFF_WIH1  (OFF_WHH0 + 6291456u)
#define OFF_WHH1  (OFF_WIH1 + 6291456u)
#define OFF_WOUT  (OFF_WHH1 + 6291456u)
#define OFF_H1ALL (OFF_WOUT + 524288u)       // bf16 h1_all[512*64][1024]
#define WS_TOTAL  (OFF_H1ALL + 67108864u)    // ~119 MB

static __device__ __forceinline__ u16 f2b(float f) {
  uint32_t u = __float_as_uint(f);
  u += 0x7FFFu + ((u >> 16) & 1u);   // round-to-nearest-even
  return (u16)(u >> 16);
}
static __device__ __forceinline__ float b2f(u16 v) {
  return __uint_as_float((uint32_t)v << 16);
}
static __device__ __forceinline__ float sigm(float x) { return 1.0f / (1.0f + __expf(-x)); }

static __device__ __forceinline__ void conv8(const u16* p, float* a) {
  const short8 w = *(const short8*)p;
#pragma unroll
  for (int j = 0; j < 8; ++j) a[j] = b2f((u16)w[j]);
}
static __device__ __forceinline__ float dot8(const u16* wp, const float* xa) {
  const short8 w = *(const short8*)wp;
  float s = 0.f;
#pragma unroll
  for (int j = 0; j < 8; ++j) s += b2f((u16)w[j]) * xa[j];
  return s;
}

// -------- f32 -> bf16 convert --------
__global__ void cvt_kernel(const float* __restrict__ src, u16* __restrict__ dst, int n) {
  int i = ((int)blockIdx.x * 256 + (int)threadIdx.x) * 4;
  if (i + 4 <= n) {
    const float4 v = *(const float4*)(src + i);
    ushort4 o;
    o.x = f2b(v.x); o.y = f2b(v.y); o.z = f2b(v.z); o.w = f2b(v.w);
    *(ushort4*)(dst + i) = o;
  }
}

// -------- embedding gather: emb_all[t*64+b][e] = bf16(embed[x[b][t]][e]) --------
__global__ void emb_kernel(const int* __restrict__ x, const float* __restrict__ embed,
                           u16* __restrict__ emb_all) {
  const int r = (int)blockIdx.x * 4 + ((int)threadIdx.x >> 6); // row = t*64+b
  const int c = ((int)threadIdx.x & 63) * 8;
  const int t = r >> 6, b = r & 63;
  const int xi = x[b * T_LEN + t];
  const float* s = embed + (size_t)xi * EMB_D + c;
  const float4 v0 = *(const float4*)s;
  const float4 v1 = *(const float4*)(s + 4);
  ushort4 lo, hi;
  lo.x = f2b(v0.x); lo.y = f2b(v0.y); lo.z = f2b(v0.z); lo.w = f2b(v0.w);
  hi.x = f2b(v1.x); hi.y = f2b(v1.y); hi.z = f2b(v1.z); hi.w = f2b(v1.w);
  u16* d = emb_all + (size_t)r * EMB_D + c;
  *(ushort4*)d = lo;
  *(ushort4*)(d + 4) = hi;
}

// -------- VALU probe superstep: layer0 computes t=s, layer1 computes t=s-1 --------
// 128 WGs x 1024 threads. WG = (layer = blockIdx>>6, unit-tile = blockIdx&63).
// Thread (u = tid>>6, b = tid&63) computes ONE (unit,batch) output via full-K
// f32 dot products on bf16 data. No MFMA, no LDS, no fragment decode.
__global__ __launch_bounds__(1024) void step_valu_kernel(
    int s,
    const u16* __restrict__ emb_all,
    const u16* __restrict__ Wih0, const u16* __restrict__ Whh0,
    const u16* __restrict__ Wih1, const u16* __restrict__ Whh1,
    const float* __restrict__ bih0, const float* __restrict__ bhh0,
    const float* __restrict__ bih1, const float* __restrict__ bhh1,
    float* __restrict__ h0f, float* __restrict__ h1f,
    u16* __restrict__ h0b, u16* __restrict__ h1b,
    u16* __restrict__ h1all)
{
  const int tid = (int)threadIdx.x;
  const int layer = (int)(blockIdx.x >> 6);
  const int ubase = ((int)blockIdx.x & 63) << 4;
  const int u = tid >> 6, b = tid & 63;
  const int ug = ubase + u;

  if (layer == 0 && s >= T_LEN) return;
  if (layer == 1 && s < 1) return;

  const int rdA = ((s + 1) & 1) * (BATCH * HID);  // slot of h0(s-1) / h-read parity
  float sr = 0.f, sz = 0.f, sni = 0.f, snh = 0.f;

  if (layer == 0) {
    // input part: emb(t=s) . Wih0 rows {ug, H+ug, 2H+ug} (len 512)
    const u16* xr = emb_all + ((size_t)s * BATCH + b) * EMB_D;
    const u16* w0 = Wih0 + (size_t)ug * EMB_D;
    const u16* w1 = Wih0 + (size_t)(HID + ug) * EMB_D;
    const u16* w2 = Wih0 + (size_t)(2 * HID + ug) * EMB_D;
    for (int e = 0; e < EMB_D; e += 8) {
      float xa[8]; conv8(xr + e, xa);
      sr  += dot8(w0 + e, xa);
      sz  += dot8(w1 + e, xa);
      sni += dot8(w2 + e, xa);
    }
    // hidden part: h0(s-1) . Whh0 rows (len 1024)
    const u16* hr = h0b + rdA + (size_t)b * HID;
    const u16* v0 = Whh0 + (size_t)ug * HID;
    const u16* v1 = Whh0 + (size_t)(HID + ug) * HID;
    const u16* v2 = Whh0 + (size_t)(2 * HID + ug) * HID;
    for (int k = 0; k < HID; k += 8) {
      float ha[8]; conv8(hr + k, ha);
      sr  += dot8(v0 + k, ha);
      sz  += dot8(v1 + k, ha);
      snh += dot8(v2 + k, ha);
    }
    const float rg = sigm(sr + bih0[ug] + bhh0[ug]);
    const float zg = sigm(sz + bih0[HID + ug] + bhh0[HID + ug]);
    const float ng = tanhf(sni + bih0[2 * HID + ug] + rg * (snh + bhh0[2 * HID + ug]));
    const int wrt = (s & 1) * (BATCH * HID);
    const float hp = h0f[rdA + b * HID + ug];
    const float hn = (1.0f - zg) * ng + zg * hp;
    h0f[wrt + b * HID + ug] = hn;
    h0b[wrt + b * HID + ug] = f2b(hn);
  } else {
    // input part: h0(s-1) . Wih1 rows (len 1024)
    const u16* xr = h0b + rdA + (size_t)b * HID;
    const u16* w0 = Wih1 + (size_t)ug * HID;
    const u16* w1 = Wih1 + (size_t)(HID + ug) * HID;
    const u16* w2 = Wih1 + (size_t)(2 * HID + ug) * HID;
    for (int k = 0; k < HID; k += 8) {
      float xa[8]; conv8(xr + k, xa);
      sr  += dot8(w0 + k, xa);
      sz  += dot8(w1 + k, xa);
      sni += dot8(w2 + k, xa);
    }
    // hidden part: h1(s-2) . Whh1 rows (len 1024)
    const int rdB = (s & 1) * (BATCH * HID);
    const u16* hr = h1b + rdB + (size_t)b * HID;
    const u16* v0 = Whh1 + (size_t)ug * HID;
    const u16* v1 = Whh1 + (size_t)(HID + ug) * HID;
    const u16* v2 = Whh1 + (size_t)(2 * HID + ug) * HID;
    for (int k = 0; k < HID; k += 8) {
      float ha[8]; conv8(hr + k, ha);
      sr  += dot8(v0 + k, ha);
      sz  += dot8(v1 + k, ha);
      snh += dot8(v2 + k, ha);
    }
    const float rg = sigm(sr + bih1[ug] + bhh1[ug]);
    const float zg = sigm(sz + bih1[HID + ug] + bhh1[HID + ug]);
    const float ng = tanhf(sni + bih1[2 * HID + ug] + rg * (snh + bhh1[2 * HID + ug]));
    const int wrt = ((s + 1) & 1) * (BATCH * HID);
    const float hp = h1f[rdB + b * HID + ug];
    const float hn = (1.0f - zg) * ng + zg * hp;
    h1f[wrt + b * HID + ug] = hn;
    const u16 hv = f2b(hn);
    h1b[wrt + b * HID + ug] = hv;
    h1all[((size_t)(s - 1) * BATCH + b) * HID + ug] = hv;
  }
}

// -------- VALU probe logits: out[b][t][v] = h1_all[t*64+b] . Wout[v] + bout[v] --------
// 8192 blocks x 1024 threads: 4 rows/block, thread = (rloc = tid>>8, v = tid&255).
__global__ __launch_bounds__(1024) void logits_valu_kernel(
    const u16* __restrict__ h1all, const u16* __restrict__ Woutb,
    const float* __restrict__ bout, float* __restrict__ out)
{
  const int tid = (int)threadIdx.x;
  const int row = (int)blockIdx.x * 4 + (tid >> 8);
  const int v = tid & 255;
  const u16* hr = h1all + (size_t)row * HID;
  const u16* wr = Woutb + (size_t)v * HID;
  float acc = bout[v];
  for (int k = 0; k < HID; k += 8) {
    float ha[8]; conv8(hr + k, ha);
    acc += dot8(wr + k, ha);
  }
  const int t = row >> 6, b = row & 63;
  out[((size_t)(b * T_LEN + t)) * VOC + v] = acc;
}

extern "C" void kernel_launch(void* const* d_in, const int* in_sizes, int n_in,
                              void* d_out, int out_size, void* d_ws, size_t ws_size,
                              hipStream_t stream) {
  const int*   x     = (const int*)d_in[0];
  const float* embed = (const float*)d_in[1];
  const float* Wih0  = (const float*)d_in[2];
  const float* Whh0  = (const float*)d_in[3];
  const float* bih0  = (const float*)d_in[4];
  const float* bhh0  = (const float*)d_in[5];
  const float* Wih1  = (const float*)d_in[6];
  const float* Whh1  = (const float*)d_in[7];
  const float* bih1  = (const float*)d_in[8];
  const float* bhh1  = (const float*)d_in[9];
  const float* Wout  = (const float*)d_in[10];
  const float* bout  = (const float*)d_in[11];
  float* out = (float*)d_out;
  char* ws = (char*)d_ws;
  if (ws_size < (size_t)WS_TOTAL) return;  // workspace too small: bail

  hipMemsetAsync(ws, 0, ZERO_BYTES, stream);  // h-state double buffers
  cvt_kernel<<<1536, 256, 0, stream>>>(Wih0, (u16*)(ws + OFF_WIH0), 3072 * 512);
  cvt_kernel<<<3072, 256, 0, stream>>>(Whh0, (u16*)(ws + OFF_WHH0), 3072 * 1024);
  cvt_kernel<<<3072, 256, 0, stream>>>(Wih1, (u16*)(ws + OFF_WIH1), 3072 * 1024);
  cvt_kernel<<<3072, 256, 0, stream>>>(Whh1, (u16*)(ws + OFF_WHH1), 3072 * 1024);
  cvt_kernel<<<256, 256, 0, stream>>>(Wout, (u16*)(ws + OFF_WOUT), 256 * 1024);
  emb_kernel<<<8192, 256, 0, stream>>>(x, embed, (u16*)(ws + OFF_EMB));

  for (int s = 0; s <= T_LEN; ++s) {
    step_valu_kernel<<<128, 1024, 0, stream>>>(
        s,
        (const u16*)(ws + OFF_EMB),
        (const u16*)(ws + OFF_WIH0), (const u16*)(ws + OFF_WHH0),
        (const u16*)(ws + OFF_WIH1), (const u16*)(ws + OFF_WHH1),
        bih0, bhh0, bih1, bhh1,
        (float*)(ws + OFF_H0F), (float*)(ws + OFF_H1F),
        (u16*)(ws + OFF_H0B), (u16*)(ws + OFF_H1B),
        (u16*)(ws + OFF_H1ALL));
  }

  logits_valu_kernel<<<8192, 1024, 0, stream>>>((const u16*)(ws + OFF_H1ALL),
                                                (const u16*)(ws + OFF_WOUT), bout, out);
}

// Round 7
// 9863.227 us; speedup vs baseline: 10.7017x; 10.7017x over previous
//
#include <hip/hip_runtime.h>
#include <stdint.h>

typedef short short8 __attribute__((ext_vector_type(8)));
typedef float f32x4 __attribute__((ext_vector_type(4)));
typedef unsigned short u16;

#define MFMA16(a, b, c) __builtin_amdgcn_mfma_f32_16x16x32_bf16((a), (b), (c), 0, 0, 0)

#define T_LEN 512
#define BATCH 64
#define EMB_D 512
#define HID 1024
#define VOC 256
#define NWG 128
#define RNN_THREADS 512

// -------- workspace layout (bytes) --------
#define OFF_H0F   0u                         // float h0[2][64][1024]
#define OFF_H1F   524288u
#define OFF_H0B   1048576u                   // bf16 h0[2][64][1024]
#define OFF_H1B   1310720u
#define ZERO_BYTES 1573120u
#define OFF_EMB   1573120u                   // bf16 emb_all[512][64][512]
#define OFF_WIH0  (OFF_EMB + 33554432u)
#define OFF_WHH0  (OFF_WIH0 + 3145728u)
#define OFF_WIH1  (OFF_WHH0 + 6291456u)
#define OFF_WHH1  (OFF_WIH1 + 6291456u)
#define OFF_WOUT  (OFF_WHH1 + 6291456u)
#define OFF_H1ALL (OFF_WOUT + 524288u)       // bf16 h1_all[512*64][1024]
#define WS_TOTAL  (OFF_H1ALL + 67108864u)

static __device__ __forceinline__ u16 f2b(float f) {
  uint32_t u = __float_as_uint(f);
  u += 0x7FFFu + ((u >> 16) & 1u);   // round-to-nearest-even
  return (u16)(u >> 16);
}
static __device__ __forceinline__ float sigm(float x) { return 1.0f / (1.0f + __expf(-x)); }

// -------- f32 -> bf16 convert --------
__global__ void cvt_kernel(const float* __restrict__ src, u16* __restrict__ dst, int n) {
  int i = ((int)blockIdx.x * 256 + (int)threadIdx.x) * 4;
  if (i + 4 <= n) {
    const float4 v = *(const float4*)(src + i);
    ushort4 o;
    o.x = f2b(v.x); o.y = f2b(v.y); o.z = f2b(v.z); o.w = f2b(v.w);
    *(ushort4*)(dst + i) = o;
  }
}

// -------- embedding gather --------
__global__ void emb_kernel(const int* __restrict__ x, const float* __restrict__ embed,
                           u16* __restrict__ emb_all) {
  const int r = (int)blockIdx.x * 4 + ((int)threadIdx.x >> 6);
  const int c = ((int)threadIdx.x & 63) * 8;
  const int t = r >> 6, b = r & 63;
  const int xi = x[b * T_LEN + t];
  const float* s = embed + (size_t)xi * EMB_D + c;
  const float4 v0 = *(const float4*)s;
  const float4 v1 = *(const float4*)(s + 4);
  ushort4 lo, hi;
  lo.x = f2b(v0.x); lo.y = f2b(v0.y); lo.z = f2b(v0.z); lo.w = f2b(v0.w);
  hi.x = f2b(v1.x); hi.y = f2b(v1.y); hi.z = f2b(v1.z); hi.w = f2b(v1.w);
  u16* d = emb_all + (size_t)r * EMB_D + c;
  *(ushort4*)d = lo;
  *(ushort4*)(d + 4) = hi;
}

// -------- superstep: layer0 computes t=s, layer1 computes t=s-1 --------
// 128 WGs: (layer = blockIdx>>6, unit-tile = blockIdx&63 -> 16 units).
// Wave-role split: waves 0-3 = input-matrix K-slices (acc2=n_i), waves 4-7 =
// hidden-matrix K-slices (acc3=n_h). Branch-free inner loop, one B source per
// wave, per-gate weight slices via SEPARATE kernel args (no in-kernel multi-MB
// constant offsets -- R6 isolated those as the miscompiled pattern).
__global__ __launch_bounds__(RNN_THREADS, 2) void step_kernel(
    int s,
    const u16* __restrict__ emb_all,
    const u16* __restrict__ A0i_r, const u16* __restrict__ A0i_z, const u16* __restrict__ A0i_n,
    const u16* __restrict__ A0h_r, const u16* __restrict__ A0h_z, const u16* __restrict__ A0h_n,
    const u16* __restrict__ A1i_r, const u16* __restrict__ A1i_z, const u16* __restrict__ A1i_n,
    const u16* __restrict__ A1h_r, const u16* __restrict__ A1h_z, const u16* __restrict__ A1h_n,
    const float* __restrict__ bih0, const float* __restrict__ bhh0,
    const float* __restrict__ bih1, const float* __restrict__ bhh1,
    float* __restrict__ h0f, float* __restrict__ h1f,
    u16* __restrict__ h0b, u16* __restrict__ h1b,
    u16* __restrict__ h1all)
{
  __shared__ __align__(16) float lds[16384];  // [zone4][group4][bt4][lane64][reg4]
  const int tid = (int)threadIdx.x;
  const int wv = tid >> 6;
  const int lane = tid & 63;
  const int lrow = lane & 15;
  const int lk8 = (lane >> 4) << 3;
  const int layer = (int)(blockIdx.x >> 6);
  const int ubase = ((int)blockIdx.x & 63) << 4;

  const bool active = (layer == 0) ? (s < T_LEN) : (s >= 1);
  if (!active) return;

  const int rdA = ((s + 1) & 1) * (BATCH * HID);  // slot of h0(s-1)
  const bool iwave = (wv < 4);

  const u16 *Ar, *Az, *An, *Bp;
  int ldb, k0, nsteps;
  if (layer == 0) {
    if (iwave) {
      Bp = emb_all + (size_t)s * (BATCH * EMB_D);
      Ar = A0i_r; Az = A0i_z; An = A0i_n;
      ldb = EMB_D; k0 = wv * 128; nsteps = 4;
    } else {
      Bp = h0b + rdA;
      Ar = A0h_r; Az = A0h_z; An = A0h_n;
      ldb = HID; k0 = (wv - 4) * 256; nsteps = 8;
    }
  } else {
    if (iwave) {
      Bp = h0b + rdA;
      Ar = A1i_r; Az = A1i_z; An = A1i_n;
      ldb = HID; k0 = wv * 256; nsteps = 8;
    } else {
      Bp = h1b + (s & 1) * (BATCH * HID);
      Ar = A1h_r; Az = A1h_z; An = A1h_n;
      ldb = HID; k0 = (wv - 4) * 256; nsteps = 8;
    }
  }

  f32x4 acc0[4], acc1[4], accn[4];
#pragma unroll
  for (int bt = 0; bt < 4; ++bt) {
    acc0[bt] = (f32x4){0.f, 0.f, 0.f, 0.f};
    acc1[bt] = (f32x4){0.f, 0.f, 0.f, 0.f};
    accn[bt] = (f32x4){0.f, 0.f, 0.f, 0.f};
  }

  const size_t arow = (size_t)(ubase + lrow) * ldb;
  for (int ks = 0; ks < nsteps; ++ks) {
    const int kk = k0 + ks * 32 + lk8;
    const short8 ar = *(const short8*)(Ar + arow + kk);
    const short8 az = *(const short8*)(Az + arow + kk);
    const short8 an = *(const short8*)(An + arow + kk);
#pragma unroll
    for (int bt = 0; bt < 4; ++bt) {
      const short8 bf = *(const short8*)(Bp + (size_t)(bt * 16 + lrow) * ldb + kk);
      acc0[bt] = MFMA16(ar, bf, acc0[bt]);
      acc1[bt] = MFMA16(az, bf, acc1[bt]);
      accn[bt] = MFMA16(an, bf, accn[bt]);
    }
  }

  // reduction round 1: i-waves (0-3) write zones; n goes to group 2, group 3 = 0
  const f32x4 z4 = {0.f, 0.f, 0.f, 0.f};
  if (iwave) {
#pragma unroll
    for (int bt = 0; bt < 4; ++bt) {
      *(f32x4*)&lds[(((wv * 4 + 0) * 4 + bt) * 64 + lane) * 4] = acc0[bt];
      *(f32x4*)&lds[(((wv * 4 + 1) * 4 + bt) * 64 + lane) * 4] = acc1[bt];
      *(f32x4*)&lds[(((wv * 4 + 2) * 4 + bt) * 64 + lane) * 4] = accn[bt];
      *(f32x4*)&lds[(((wv * 4 + 3) * 4 + bt) * 64 + lane) * 4] = z4;
    }
  }
  __syncthreads();
  // reduction round 2: h-waves (4-7) add; n goes to group 3
  if (!iwave) {
    const int z = wv - 4;
#pragma unroll
    for (int bt = 0; bt < 4; ++bt) {
      float* p0 = &lds[(((z * 4 + 0) * 4 + bt) * 64 + lane) * 4];
      float* p1 = &lds[(((z * 4 + 1) * 4 + bt) * 64 + lane) * 4];
      float* p3 = &lds[(((z * 4 + 3) * 4 + bt) * 64 + lane) * 4];
      f32x4 v0 = *(f32x4*)p0; v0 += acc0[bt]; *(f32x4*)p0 = v0;
      f32x4 v1 = *(f32x4*)p1; v1 += acc1[bt]; *(f32x4*)p1 = v1;
      f32x4 v3 = *(f32x4*)p3; v3 += accn[bt]; *(f32x4*)p3 = v3;
    }
  }
  __syncthreads();
  // epilogue: decode-0 (validated TEST B), gate math + state writes (validated R3)
  {
    const int wrt = (layer == 0) ? (s & 1) * (BATCH * HID) : ((s + 1) & 1) * (BATCH * HID);
    const int rdh = (layer == 0) ? ((s + 1) & 1) * (BATCH * HID) : (s & 1) * (BATCH * HID);
    const float* bi = layer ? bih1 : bih0;
    const float* bh = layer ? bhh1 : bhh0;
    float* hf = layer ? h1f : h0f;
    u16* hb = layer ? h1b : h0b;
#pragma unroll
    for (int pp = 0; pp < 2; ++pp) {
      const int p = tid + pp * RNN_THREADS;  // (u,b): u = p>>6, b = p&63
      const int u = p >> 6, b = p & 63;
      const int l = ((u >> 2) << 4) | (b & 15);
      const int r = u & 3;
      const int bt = b >> 4;
      float sr = 0.f, sz = 0.f, sni = 0.f, snh = 0.f;
#pragma unroll
      for (int z = 0; z < 4; ++z) {
        sr  += lds[(((z * 4 + 0) * 4 + bt) * 64 + l) * 4 + r];
        sz  += lds[(((z * 4 + 1) * 4 + bt) * 64 + l) * 4 + r];
        sni += lds[(((z * 4 + 2) * 4 + bt) * 64 + l) * 4 + r];
        snh += lds[(((z * 4 + 3) * 4 + bt) * 64 + l) * 4 + r];
      }
      const int ug = ubase + u;
      const float rg = sigm(sr + bi[ug] + bh[ug]);
      const float zg = sigm(sz + bi[HID + ug] + bh[HID + ug]);
      const float ng = tanhf(sni + bi[2 * HID + ug] + rg * (snh + bh[2 * HID + ug]));
      const float hp = hf[rdh + b * HID + ug];
      const float hn = (1.0f - zg) * ng + zg * hp;
      hf[wrt + b * HID + ug] = hn;
      const u16 hv = f2b(hn);
      hb[wrt + b * HID + ug] = hv;
      if (layer) h1all[((size_t)(s - 1) * BATCH + b) * HID + ug] = hv;
    }
  }
}

// -------- epilogue logits (R5-verified MFMA path, decode-0) --------
__global__ __launch_bounds__(256, 2) void logits_kernel(
    const u16* __restrict__ h1all, const u16* __restrict__ Woutb,
    const float* __restrict__ bout, float* __restrict__ out)
{
  __shared__ __align__(16) short lds[16 * 4 * 64 * 8];
  const int tid = (int)threadIdx.x;
  const int wv = tid >> 6, lane = tid & 63;
  const int lrow = lane & 15, lk8 = (lane >> 4) << 3;
  const int row0 = (int)blockIdx.x * 64 + wv * 16;
  f32x4 acc[16];
#pragma unroll
  for (int i = 0; i < 16; ++i) acc[i] = (f32x4){0.f, 0.f, 0.f, 0.f};

  for (int kc = 0; kc < HID; kc += 128) {
    __syncthreads();
#pragma unroll
    for (int j = 0; j < 16; ++j) {
      const int slot = tid + j * 256;
      const int ct = slot >> 8, kt = (slot >> 6) & 3, l = slot & 63;
      *(short8*)&lds[slot * 8] =
          *(const short8*)(Woutb + (size_t)(ct * 16 + (l & 15)) * HID + kc + kt * 32 + ((l >> 4) << 3));
    }
    __syncthreads();
#pragma unroll
    for (int kt = 0; kt < 4; ++kt) {
      const short8 af = *(const short8*)(h1all + (size_t)(row0 + lrow) * HID + kc + kt * 32 + lk8);
#pragma unroll
      for (int ct = 0; ct < 16; ++ct) {
        const short8 bf = *(const short8*)&lds[((ct * 4 + kt) * 64 + lane) * 8];
        acc[ct] = MFMA16(af, bf, acc[ct]);
      }
    }
  }
#pragma unroll
  for (int ct = 0; ct < 16; ++ct) {
    const int v = ct * 16 + lrow;
    const float bo = bout[v];
#pragma unroll
    for (int r = 0; r < 4; ++r) {
      const int row = row0 + (lane >> 4) * 4 + r;  // row = t*64 + b
      const int t = row >> 6, b = row & 63;
      out[((size_t)(b * T_LEN + t)) * VOC + v] = acc[ct][r] + bo;
    }
  }
}

extern "C" void kernel_launch(void* const* d_in, const int* in_sizes, int n_in,
                              void* d_out, int out_size, void* d_ws, size_t ws_size,
                              hipStream_t stream) {
  const int*   x     = (const int*)d_in[0];
  const float* embed = (const float*)d_in[1];
  const float* Wih0  = (const float*)d_in[2];
  const float* Whh0  = (const float*)d_in[3];
  const float* bih0  = (const float*)d_in[4];
  const float* bhh0  = (const float*)d_in[5];
  const float* Wih1  = (const float*)d_in[6];
  const float* Whh1  = (const float*)d_in[7];
  const float* bih1  = (const float*)d_in[8];
  const float* bhh1  = (const float*)d_in[9];
  const float* Wout  = (const float*)d_in[10];
  const float* bout  = (const float*)d_in[11];
  float* out = (float*)d_out;
  char* ws = (char*)d_ws;
  if (ws_size < (size_t)WS_TOTAL) return;

  hipMemsetAsync(ws, 0, ZERO_BYTES, stream);  // h-state double buffers
  cvt_kernel<<<1536, 256, 0, stream>>>(Wih0, (u16*)(ws + OFF_WIH0), 3072 * 512);
  cvt_kernel<<<3072, 256, 0, stream>>>(Whh0, (u16*)(ws + OFF_WHH0), 3072 * 1024);
  cvt_kernel<<<3072, 256, 0, stream>>>(Wih1, (u16*)(ws + OFF_WIH1), 3072 * 1024);
  cvt_kernel<<<3072, 256, 0, stream>>>(Whh1, (u16*)(ws + OFF_WHH1), 3072 * 1024);
  cvt_kernel<<<256, 256, 0, stream>>>(Wout, (u16*)(ws + OFF_WOUT), 256 * 1024);
  emb_kernel<<<8192, 256, 0, stream>>>(x, embed, (u16*)(ws + OFF_EMB));

  // host-side per-gate weight slices (rows: [0,H)=r, [H,2H)=z, [2H,3H)=n)
  const u16* wih0b = (const u16*)(ws + OFF_WIH0);
  const u16* whh0b = (const u16*)(ws + OFF_WHH0);
  const u16* wih1b = (const u16*)(ws + OFF_WIH1);
  const u16* whh1b = (const u16*)(ws + OFF_WHH1);
  const u16* A0i_r = wih0b;             // [1024][512]
  const u16* A0i_z = wih0b + 524288;
  const u16* A0i_n = wih0b + 1048576;
  const u16* A0h_r = whh0b;             // [1024][1024]
  const u16* A0h_z = whh0b + 1048576;
  const u16* A0h_n = whh0b + 2097152;
  const u16* A1i_r = wih1b;
  const u16* A1i_z = wih1b + 1048576;
  const u16* A1i_n = wih1b + 2097152;
  const u16* A1h_r = whh1b;
  const u16* A1h_z = whh1b + 1048576;
  const u16* A1h_n = whh1b + 2097152;

  for (int s = 0; s <= T_LEN; ++s) {
    step_kernel<<<NWG, RNN_THREADS, 0, stream>>>(
        s, (const u16*)(ws + OFF_EMB),
        A0i_r, A0i_z, A0i_n, A0h_r, A0h_z, A0h_n,
        A1i_r, A1i_z, A1i_n, A1h_r, A1h_z, A1h_n,
        bih0, bhh0, bih1, bhh1,
        (float*)(ws + OFF_H0F), (float*)(ws + OFF_H1F),
        (u16*)(ws + OFF_H0B), (u16*)(ws + OFF_H1B),
        (u16*)(ws + OFF_H1ALL));
  }

  logits_kernel<<<512, 256, 0, stream>>>((const u16*)(ws + OFF_H1ALL),
                                         (const u16*)(ws + OFF_WOUT), bout, out);
}